// Round 4
// baseline (21.750 us; speedup 1.0000x reference)
//
#include <hip/hip_runtime.h>

#define NPROTO 20
#define SEQ_LEN 512
#define LPT 4            // l-positions per thread
#define TPB (SEQ_LEN / LPT)   // 128 threads, one block per batch row

// Correctly-rounded a/d via Markstein refinement, given rc = RN(1/d) and
// nd = -d. Markstein's RN-quotient theorem: q0 = RN(a*rc), r = fma(nd,q0,a)
// (exact), q1 = RN(q0 + r*rc) == RN(a/d). Verified bit-exact vs the harness
// in R3 (absmax=0 over the full input set) for both divisor families here:
//  - d = 3.0f (constant)
//  - d = integer in [1,510], a = exact integer product < 2^18
__device__ __forceinline__ float div_exact(float a, float nd, float rc)
{
    const float q0 = a * rc;
    const float r  = fmaf(nd, q0, a);
    return fmaf(r, rc, q0);
}

// One block per batch row. 128 threads, 4 consecutive positions per thread.
// Inner loop: 1 ds_read_b128 per kept prototype (params broadcast), pure VALU
// otherwise. All f32 ops replicate the reference's exact order/associativity;
// the only IEEE divides run in the 20-lane setup phase (1/den) and the t==0
// mean (s/20.0f).
__global__ __launch_bounds__(TPB)
void adaptive_mask_kernel(const float* __restrict__ tok,
                          const float* __restrict__ sigma,
                          const float* __restrict__ pi,
                          float* __restrict__ out)
{
    const int b = blockIdx.x;
    const int t = threadIdx.x;

    __shared__ float4 s_p4[NPROTO];   // {m, aL, aR, rc=RN(1/den)}
    __shared__ float  s_pi[NPROTO];
    __shared__ unsigned s_kmask;

    if (t < NPROTO) {
        const int idx = b * NPROTO + t;
        const float tk = tok[idx];
        const float sg = sigma[idx];
        const float m  = rintf(fminf(fmaxf(tk, 1.0f), 511.0f)); // round-half-even
        const float aL = (0.001f * sg) * m;                     // CVL*sigma*m
        const float aR = (0.001f * sg) * (512.0f - m);          // CVR*sigma*(512-m)
        const float den = (m == 511.0f) ? 1.0f : (511.0f - m);
        const float rc  = 1.0f / den;                           // IEEE RN(1/den)
        s_p4[t] = make_float4(m, aL, aR, rc);
        s_pi[t] = pi[idx];
    }
    __syncthreads();

    if (t == 0) {
        float s = 0.0f;
        for (int p = 0; p < NPROTO; ++p) s += s_pi[p];   // sequential, like XLA
        const float mean = s / 20.0f;
        unsigned kmv = 0;
        for (int p = 0; p < NPROTO; ++p)
            if (s_pi[p] >= mean) kmv |= (1u << p);
        s_kmask = kmv;
    }
    __syncthreads();

    const unsigned km = __builtin_amdgcn_readfirstlane(s_kmask);
    const float C3 = 1.0f / 3.0f;     // RN(1/3)

    // l = LPT*t + j, j = 0..3 (consecutive -> float4 store)
    const float lf0 = (float)(LPT * t);
    const float lf1 = lf0 + 1.0f;     // exact (integers < 512)
    const float lf2 = lf0 + 2.0f;
    const float lf3 = lf0 + 3.0f;
    float acc0 = 0.0f, acc1 = 0.0f, acc2 = 0.0f, acc3 = 0.0f;

    #pragma unroll
    for (int p = 0; p < NPROTO; ++p) {
        if (!((km >> p) & 1u)) continue;     // dropped prototype == exact 0
        const float4 P = s_p4[p];            // one ds_read_b128, broadcast
        const float m = P.x, aL = P.y, aR = P.z, rc = P.w;
        const float msub   = m - 512.0f;                          // exact
        const float negden = (m == 511.0f) ? -1.0f : (m - 511.0f);// -den, exact

#define EVAL(LF, ACC)                                                       \
        {                                                                   \
            const float q    = (LF) - m;                                    \
            const float num  = q * msub;              /* exact int prod */  \
            const float rq   = div_exact(num, negden, rc);                  \
            const float left = (q + 1.0f) + aL;                             \
            const float rt   = (-1.0f + rq) + aR;                           \
            const float base = ((LF) < m) ? left : rt;                      \
            (ACC) += div_exact(base, -3.0f, C3) + 1.0f;                     \
        }

        EVAL(lf0, acc0)
        EVAL(lf1, acc1)
        EVAL(lf2, acc2)
        EVAL(lf3, acc3)
#undef EVAL
    }

    float4 res;
    res.x = (acc0 > 0.0f) ? 1.0f : 0.0f;
    res.y = (acc1 > 0.0f) ? 1.0f : 0.0f;
    res.z = (acc2 > 0.0f) ? 1.0f : 0.0f;
    res.w = (acc3 > 0.0f) ? 1.0f : 0.0f;
    *reinterpret_cast<float4*>(out + (size_t)b * SEQ_LEN + LPT * t) = res;
}

extern "C" void kernel_launch(void* const* d_in, const int* in_sizes, int n_in,
                              void* d_out, int out_size, void* d_ws, size_t ws_size,
                              hipStream_t stream)
{
    const float* tok   = (const float*)d_in[0];
    const float* sigma = (const float*)d_in[1];
    const float* pi    = (const float*)d_in[2];
    float* out = (float*)d_out;

    const int B = in_sizes[0] / NPROTO;   // 8192
    adaptive_mask_kernel<<<B, TPB, 0, stream>>>(tok, sigma, pi, out);
}